// Round 6
// baseline (4556.573 us; speedup 1.0000x reference)
//
#include <hip/hip_runtime.h>
#include <cmath>
#include <cstdint>

typedef unsigned int u32;
typedef unsigned long long u64;

#define A_TOT   159882
#define PRE_NMS 4000
#define POST_NMS 1000
#define NWORDS  63            // ceil(4000/64)
#define HIST_BINS 131072
#define HIST2_BINS 32768
#define SURV_CAP 8192
#define MONO_NEG_INF 0x007FFFFFu
#define XSTRIP 24

struct BaseTab { float v[60]; };   // [level][aspect][4]

__device__ inline u32 mono32f(float s) {
    u32 u = __float_as_uint(s);
    return (u & 0x80000000u) ? ~u : (u | 0x80000000u);
}

// XLA:CPU / cephes vectorized expf (Horner, FMA, m=0-exact for |x|<0.3466)
__device__ inline float pexp_f(float x0) {
    float x = fminf(x0, 88.3762626647950f);
    x = fmaxf(x, -88.3762626647949f);
    float m = floorf(__builtin_fmaf(x, 1.44269504088896341f, 0.5f));
    float r = __builtin_fmaf(m, -0.693359375f, x);
    r = __builtin_fmaf(m, 2.12194440e-4f, r);
    float z = r * r;
    float y = 1.9875691500E-4f;
    y = __builtin_fmaf(y, r, 1.3981999507E-3f);
    y = __builtin_fmaf(y, r, 8.3334519073E-3f);
    y = __builtin_fmaf(y, r, 4.1665795894E-2f);
    y = __builtin_fmaf(y, r, 1.6666665459E-1f);
    y = __builtin_fmaf(y, r, 5.0000001201E-1f);
    y = __builtin_fmaf(y, z, r);
    y = y + 1.0f;
    return ldexpf(y, (int)m);
}

// np/jax-exact f32 decode chain (no fma, op order preserved). Returns box, sets valid.
__device__ inline float4 decode_box(const float* __restrict__ reg,
                                    const float* __restrict__ anc,
                                    u32 i, bool* valid) {
#pragma clang fp contract(off)
    float x1 = anc[4 * i], y1 = anc[4 * i + 1], x2 = anc[4 * i + 2], y2 = anc[4 * i + 3];
    float acx = (x2 + x1) / 2.0f, acy = (y2 + y1) / 2.0f;
    float aw = x2 - x1, ah = y2 - y1;
    float t0 = reg[4 * i], t1 = reg[4 * i + 1], t2 = reg[4 * i + 2], t3 = reg[4 * i + 3];
    float cx = (t0 * aw) + acx;
    float cy = (t1 * ah) + acy;
    float w  = pexp_f(t2) * aw;
    float hh = pexp_f(t3) * ah;
    float bx1 = fminf(fmaxf(cx - w / 2.0f, 0.f), 1.f);
    float by1 = fminf(fmaxf(cy - hh / 2.0f, 0.f), 1.f);
    float bx2 = fminf(fmaxf(cx + w / 2.0f, 0.f), 1.f);
    float by2 = fminf(fmaxf(cy + hh / 2.0f, 0.f), 1.f);
    float wsz = bx2 - bx1, hsz = by2 - by1;
    *valid = (hsz >= 0.01f) && (wsz >= 0.01f);
    return make_float4(bx1, by1, bx2, by2);
}

// ---------------------------------------------------------------- W transpose to (ky,kx,c)-major
// Wt[knew][co], knew = (ky*3+kx)*256 + c  (NHWC im2col contraction order, c innermost)
__global__ __launch_bounds__(256) void wt_k(const float* __restrict__ w,
                                            float* __restrict__ Wt) {
    int i = blockIdx.x * 256 + threadIdx.x;
    if (i >= 2304 * 256) return;
    int co = i & 255, knew = i >> 8;
    int g = knew >> 8;          // ky*3+kx
    int c = knew & 255;
    Wt[knew * 256 + co] = w[co * 2304 + c * 9 + g];
}

// ---------------------------------------------------------------- fused conv3x3 + relu + heads
// Eigen-AVX (no FMA) semantics: per output element, K=2304 split into 8 panels
// of kc=288; each panel = sequential (mul,add) chain in k=(ky,kx,c) ascending;
// panels combined by left-assoc plain adds. Heads: K=256 single (mul,add) chain.
// grid: (ceil(gw/24), gh), block 192.
__global__ __launch_bounds__(192) void conv_head_fused(
    const float* __restrict__ feat, const float* __restrict__ Wt,
    const float* __restrict__ b_inter,
    const float* __restrict__ wc, const float* __restrict__ bc,
    const float* __restrict__ wr, const float* __restrict__ br,
    float* __restrict__ cls_out, float* __restrict__ reg_out,
    int gh, int gw, int abase)
{
#pragma clang fp contract(off)
    __shared__ __align__(16) char smraw[36864];
    float (*Ws)[256] = (float(*)[256])smraw;             // 32 KB  (phase 1)
    float (*Xs)[24]  = (float(*)[24])(smraw + 32768);    // 3 KB   (phase 1)
    float* hsh       = (float*)smraw;                    // 24 KB = 256 x 24 (phase 2)

    const int t  = threadIdx.x;
    const int y  = blockIdx.y;
    const int x0 = blockIdx.x * XSTRIP;
    const int cg = t & 31;      // 32 groups of 8 c_out
    const int xg = t >> 5;      // 6 groups of 4 x

    float tacc[8][4], pacc[8][4];
#pragma unroll
    for (int a = 0; a < 8; ++a)
#pragma unroll
        for (int b = 0; b < 4; ++b) { tacc[a][b] = 0.f; pacc[a][b] = 0.f; }

    int stepc = 0;
    // g ascending (outer), c-blocks ascending, kk ascending -> k ascending
    for (int g = 0; g < 9; ++g) {
        int ky = g / 3, kx = g - ky * 3;
        int yy = y + ky - 1;
        for (int cb = 0; cb < 256; cb += 32) {
            __syncthreads();
            // stage Ws: 32 rows x 256 co
            for (int f4 = t; f4 < 2048; f4 += 192) {
                int row = f4 >> 6, c4 = (f4 & 63) << 2;
                *(float4*)&Ws[row][c4] =
                    *(const float4*)&Wt[((g * 256 + cb + row) * 256) + c4];
            }
            // stage Xs: 32 channel rows x 24 cols at fixed (yy, kx) shift
            for (int idx = t; idx < 32 * 24; idx += 192) {
                int row = idx / 24, j = idx - row * 24;
                int c = cb + row;
                int xcol = x0 + kx - 1 + j;
                float v = 0.f;
                if (yy >= 0 && yy < gh && xcol >= 0 && xcol < gw)
                    v = feat[(c * gh + yy) * gw + xcol];
                Xs[row][j] = v;
            }
            __syncthreads();
#pragma unroll 4
            for (int kk = 0; kk < 32; ++kk) {
                float wv[8], xv[4];
#pragma unroll
                for (int a = 0; a < 8; ++a) wv[a] = Ws[kk][cg * 8 + a];
#pragma unroll
                for (int b = 0; b < 4; ++b) xv[b] = Xs[kk][xg * 4 + b];
#pragma unroll
                for (int a = 0; a < 8; ++a)
#pragma unroll
                    for (int b = 0; b < 4; ++b) {
                        float prod = wv[a] * xv[b];       // separate round (AVX, no FMA)
                        pacc[a][b] = pacc[a][b] + prod;   // separate round
                    }
            }
            ++stepc;
            if ((stepc % 9) == 0) {   // k multiple of 288: flush panel partial
#pragma unroll
                for (int a = 0; a < 8; ++a)
#pragma unroll
                    for (int b = 0; b < 4; ++b) {
                        tacc[a][b] = tacc[a][b] + pacc[a][b];
                        pacc[a][b] = 0.f;
                    }
            }
        }
    }
    __syncthreads();

    // h = f32 relu(conv + bias) -> LDS
#pragma unroll
    for (int a = 0; a < 8; ++a) {
        int c = cg * 8 + a;
        float hb = b_inter[c];
#pragma unroll
        for (int b = 0; b < 4; ++b) {
            float hv = tacc[a][b] + hb;
            hsh[c * XSTRIP + xg * 4 + b] = fmaxf(hv, 0.f);
        }
    }
    __syncthreads();

    // heads: 18 channels x 24 x ; single sequential (mul,add) chain over c ascending
    int xl = t % 24;
    int g2 = t / 24;            // 0..7
    int xabs = x0 + xl;
    bool xin = (xabs < gw);
    int s = y * gw + xabs;
    long b2 = (long)abase + (long)s * 3;
    for (int ch = g2; ch < 18; ch += 8) {
        const float* wp = (ch < 6) ? (wc + ch * 256) : (wr + (ch - 6) * 256);
        float a2 = 0.f;
        for (int c = 0; c < 256; ++c) {
            float prod = wp[c] * hsh[c * XSTRIP + xl];
            a2 = a2 + prod;
        }
        if (xin) {
            if (ch < 6) {
                float v = a2 + bc[ch];
                int aa = ch >> 1, c2 = ch & 1;
                cls_out[(b2 + aa) * 2 + c2] = v;
            } else {
                int rch = ch - 6;
                float v = a2 + br[rch];
                int aa = rch >> 2, dd = rch & 3;
                reg_out[(b2 + aa) * 4 + dd] = v;
            }
        }
    }
}

// ---------------------------------------------------------------- anchors
__global__ __launch_bounds__(256) void anchors_k(float* __restrict__ anc, BaseTab bt) {
#pragma clang fp contract(off)
    int i = blockIdx.x * 256 + threadIdx.x;
    if (i >= A_TOT) return;
    int l, base, gw, str;
    if (i < 120000)      { l = 0; base = 0;      gw = 200; str = 4;  }
    else if (i < 150000) { l = 1; base = 120000; gw = 100; str = 8;  }
    else if (i < 157500) { l = 2; base = 150000; gw = 50;  str = 16; }
    else if (i < 159375) { l = 3; base = 157500; gw = 25;  str = 32; }
    else                 { l = 4; base = 159375; gw = 13;  str = 61; }
    int j = i - base;
    int s = j / 3;
    int a = j - s * 3;
    int y = s / gw;
    int x = s - y * gw;
    float sx = (float)(x * str), sy = (float)(y * str);
    const float* bb = &bt.v[(l * 3 + a) * 4];
    anc[4 * i + 0] = (sx + bb[0]) / 800.0f;
    anc[4 * i + 1] = (sy + bb[1]) / 800.0f;
    anc[4 * i + 2] = (sx + bb[2]) / 800.0f;
    anc[4 * i + 3] = (sy + bb[3]) / 800.0f;
}

// ---------------------------------------------------------------- f32 score + key + hist
__global__ __launch_bounds__(256) void score_k(
    const float* __restrict__ cls, const float* __restrict__ reg,
    const float* __restrict__ anc,
    u64* __restrict__ keys, u32* __restrict__ hist)
{
#pragma clang fp contract(off)
    int i = blockIdx.x * 256 + threadIdx.x;
    if (i >= A_TOT) return;
    float l0 = cls[2 * i], l1 = cls[2 * i + 1];
    float m  = fmaxf(l0, l1);
    float e0 = pexp_f(l0 - m);
    float e1 = pexp_f(l1 - m);
    float sum = e0 + e1;
    float sc  = e1 / sum;

    bool valid;
    (void)decode_box(reg, anc, (u32)i, &valid);
    float score = valid ? sc : -INFINITY;
    u32 u = mono32f(score);
    keys[i] = ((u64)u << 32) | (u32)(~(u32)i);   // desc score, asc index
    atomicAdd(&hist[u >> 15], 1u);
}

// ---------------------------------------------------------------- coarse threshold bin
__global__ __launch_bounds__(1024) void topk_thresh(const u32* __restrict__ hist,
                                                    u32* __restrict__ counters) {
    __shared__ u32 part[1024];
    int t = threadIdx.x;
    u32 s = 0;
    for (int q = 0; q < 128; ++q) s += hist[HIST_BINS - 1 - (t * 128 + q)];
    part[t] = s;
    __syncthreads();
    if (t == 0) {
        u32 cum = 0, cumBefore = 0;
        int tc = 1023;
        for (int c = 0; c < 1024; ++c) {
            if (cum + part[c] >= PRE_NMS) { tc = c; cumBefore = cum; break; }
            cum += part[c];
        }
        u32 cum2 = cumBefore;
        int bstar = 0;
        for (int q = 0; q < 128; ++q) {
            int b = HIST_BINS - 1 - (tc * 128 + q);
            u32 hv = hist[b];
            if (cum2 + hv >= PRE_NMS) { bstar = b; break; }
            cum2 += hv;
        }
        counters[0] = (u32)bstar;
        counters[1] = cum2;
    }
}

// ---------------------------------------------------------------- fine histogram in bstar bin
__global__ __launch_bounds__(256) void hist2_k(const u64* __restrict__ keys,
                                               const u32* __restrict__ counters,
                                               u32* __restrict__ hist2) {
    int i = blockIdx.x * 256 + threadIdx.x;
    if (i >= A_TOT) return;
    u32 u = (u32)(keys[i] >> 32);
    if ((u >> 15) == counters[0]) atomicAdd(&hist2[u & 0x7FFF], 1u);
}

// ---------------------------------------------------------------- exact 32-bit cutoff
__global__ __launch_bounds__(1024) void thresh2_k(const u32* __restrict__ hist2,
                                                  u32* __restrict__ counters) {
    __shared__ u32 part[1024];
    int t = threadIdx.x;
    u32 s = 0;
    for (int q = 0; q < 32; ++q) s += hist2[HIST2_BINS - 1 - (t * 32 + q)];
    part[t] = s;
    __syncthreads();
    if (t == 0) {
        u32 bstar = counters[0];
        u32 cum = counters[1];
        int tc = 1023;
        u32 cumBefore = cum;
        for (int c = 0; c < 1024; ++c) {
            if (cum + part[c] >= PRE_NMS) { tc = c; cumBefore = cum; break; }
            cum += part[c];
        }
        u32 cum2 = cumBefore;
        u32 low = 0;
        for (int q = 0; q < 32; ++q) {
            int b = HIST2_BINS - 1 - (tc * 32 + q);
            u32 hv = hist2[b];
            if (cum2 + hv >= PRE_NMS) { low = (u32)b; break; }
            cum2 += hv;
        }
        counters[3] = (bstar << 15) | low;   // exact monotone-u cutoff
    }
}

// ---------------------------------------------------------------- compact survivors (exact)
__global__ __launch_bounds__(256) void compact_k(const u64* __restrict__ keys,
                                                 u32* __restrict__ counters,
                                                 u64* __restrict__ surv) {
    int i = blockIdx.x * 256 + threadIdx.x;
    if (i >= A_TOT) return;
    u32 cut = counters[3];
    u64 k = keys[i];
    if ((u32)(k >> 32) >= cut) {
        u32 slot = atomicAdd(&counters[2], 1u);
        if (slot < SURV_CAP) surv[slot] = k;
    }
}

// ---------------------------------------------------------------- bitonic sort + gather (recompute decode)
__global__ __launch_bounds__(1024) void sort_topk(
    const u64* __restrict__ surv, const u32* __restrict__ counters,
    const float* __restrict__ reg, const float* __restrict__ anc,
    float* __restrict__ boxes4k, u64* __restrict__ finmask)
{
    __shared__ u64 K[SURV_CAP];   // 64 KB
    int t = threadIdx.x;
    u32 n = counters[2];
    if (n > SURV_CAP) n = SURV_CAP;
    for (int p = t; p < SURV_CAP; p += 1024) K[p] = (p < (int)n) ? surv[p] : 0ull;
    __syncthreads();
    for (int k = 2; k <= SURV_CAP; k <<= 1) {
        for (int j = k >> 1; j > 0; j >>= 1) {
            for (int p = t; p < SURV_CAP / 2; p += 1024) {
                int i = 2 * p - (p & (j - 1));
                int pr = i + j;
                bool desc = ((i & k) == 0);
                u64 a = K[i], b = K[pr];
                if (desc ? (a < b) : (a > b)) { K[i] = b; K[pr] = a; }
            }
            __syncthreads();
        }
    }
    for (int jj = t; jj < PRE_NMS; jj += 1024) {
        u64 key = K[jj];
        u32 u = (u32)(key >> 32);
        float b0 = 0.f, b1 = 0.f, b2 = 0.f, b3 = 0.f;
        if (u > MONO_NEG_INF) {
            u32 idx = ~(u32)key;
            bool valid;
            float4 bx = decode_box(reg, anc, idx, &valid);
            b0 = bx.x; b1 = bx.y; b2 = bx.z; b3 = bx.w;
        }
        boxes4k[4 * jj + 0] = b0;
        boxes4k[4 * jj + 1] = b1;
        boxes4k[4 * jj + 2] = b2;
        boxes4k[4 * jj + 3] = b3;
    }
    if (t < NWORDS) {
        u64 wmask = 0;
        for (int b = 0; b < 64; ++b) {
            int jj = t * 64 + b;
            if (jj < PRE_NMS) {
                u32 u = (u32)(K[jj] >> 32);
                if (u > MONO_NEG_INF) wmask |= (1ull << b);
            }
        }
        finmask[t] = wmask;
    }
}

// ---------------------------------------------------------------- suppression matrix (f32, np op order)
__global__ __launch_bounds__(64) void supmat_k(const float* __restrict__ boxes4k,
                                               u64* __restrict__ sup) {
#pragma clang fp contract(off)
    __shared__ float cb[64][4];
    int rb = blockIdx.y, cbk = blockIdx.x;
    int tl = threadIdx.x;
    int j = cbk * 64 + tl;
    if (j < PRE_NMS) {
        cb[tl][0] = boxes4k[4 * j + 0];
        cb[tl][1] = boxes4k[4 * j + 1];
        cb[tl][2] = boxes4k[4 * j + 2];
        cb[tl][3] = boxes4k[4 * j + 3];
    } else {
        cb[tl][0] = cb[tl][1] = cb[tl][2] = cb[tl][3] = 0.f;
    }
    __syncthreads();
    int i = rb * 64 + tl;
    if (i >= PRE_NMS) return;
    float ax1 = boxes4k[4 * i + 0], ay1 = boxes4k[4 * i + 1];
    float ax2 = boxes4k[4 * i + 2], ay2 = boxes4k[4 * i + 3];
    float aarea = fmaxf(ax2 - ax1, 0.f) * fmaxf(ay2 - ay1, 0.f);
    u64 w = 0;
    for (int q = 0; q < 64; ++q) {
        int jg = cbk * 64 + q;
        if (jg >= PRE_NMS || jg <= i) continue;
        float bx1 = cb[q][0], by1 = cb[q][1], bx2 = cb[q][2], by2 = cb[q][3];
        float barea = fmaxf(bx2 - bx1, 0.f) * fmaxf(by2 - by1, 0.f);
        float lx = fmaxf(ax1, bx1), ly = fmaxf(ay1, by1);
        float rx = fminf(ax2, bx2), ry = fminf(ay2, by2);
        float iw = fmaxf(rx - lx, 0.f), ih = fmaxf(ry - ly, 0.f);
        float inter = iw * ih;
        float uni = (aarea + barea) - inter;
        float iou = (uni > 0.f) ? inter / uni : 0.f;
        if (iou > 0.7f) w |= (1ull << q);
    }
    sup[(size_t)i * NWORDS + cbk] = w;
}

// ---------------------------------------------------------------- sequential NMS scan
__device__ inline u64 shfl_u64(u64 v, int lane) {
    int lo = __shfl((int)(u32)(v & 0xFFFFFFFFull), lane, 64);
    int hi = __shfl((int)(u32)(v >> 32), lane, 64);
    return ((u64)(u32)hi << 32) | (u32)lo;
}

__global__ __launch_bounds__(64) void nms_scan_k(const u64* __restrict__ sup,
                                                 const u64* __restrict__ finmask,
                                                 u64* __restrict__ keepw) {
    int lane = threadIdx.x;
    u64 keep = (lane < NWORDS) ? finmask[lane] : 0ull;
    u64 cur[8], nxt[8];
#pragma unroll
    for (int q = 0; q < 8; ++q)
        cur[q] = (lane < NWORDS) ? sup[(size_t)q * NWORDS + lane] : 0ull;
    for (int base = 0; base < PRE_NMS; base += 8) {
        int nb = base + 8;
#pragma unroll
        for (int q = 0; q < 8; ++q) {
            int i = nb + q;
            nxt[q] = (lane < NWORDS && i < PRE_NMS) ? sup[(size_t)i * NWORDS + lane] : 0ull;
        }
#pragma unroll
        for (int q = 0; q < 8; ++q) {
            int i = base + q;
            int wi = i >> 6, bi = i & 63;
            u64 kw = shfl_u64(keep, wi);
            if ((kw >> bi) & 1ull) keep &= ~cur[q];
        }
#pragma unroll
        for (int q = 0; q < 8; ++q) cur[q] = nxt[q];
    }
    if (lane < NWORDS) keepw[lane] = keep;
}

// ---------------------------------------------------------------- final compaction
__global__ __launch_bounds__(1024) void output_k(const u64* __restrict__ keepw,
                                                 const float* __restrict__ boxes4k,
                                                 float* __restrict__ roi_out) {
    __shared__ u32 pref[NWORDS + 1];
    int t = threadIdx.x;
    if (t == 0) {
        u32 run = 0;
        for (int w = 0; w < NWORDS; ++w) { pref[w] = run; run += (u32)__popcll(keepw[w]); }
        pref[NWORDS] = run;
    }
    __syncthreads();
    u32 total = pref[NWORDS];
    u32 nk = total < (u32)POST_NMS ? total : (u32)POST_NMS;
    for (int j = t; j < PRE_NMS; j += 1024) {
        int wi = j >> 6, bi = j & 63;
        u64 kw = keepw[wi];
        if ((kw >> bi) & 1ull) {
            u32 rank = pref[wi] + (u32)__popcll(kw & ((1ull << bi) - 1ull));
            if (rank < (u32)POST_NMS) {
                roi_out[4 * rank + 0] = boxes4k[4 * j + 0];
                roi_out[4 * rank + 1] = boxes4k[4 * j + 1];
                roi_out[4 * rank + 2] = boxes4k[4 * j + 2];
                roi_out[4 * rank + 3] = boxes4k[4 * j + 3];
            }
        }
    }
    for (int r2 = t; r2 < POST_NMS; r2 += 1024) {
        if ((u32)r2 >= nk) {
            roi_out[4 * r2 + 0] = 0.f;
            roi_out[4 * r2 + 1] = 0.f;
            roi_out[4 * r2 + 2] = 0.f;
            roi_out[4 * r2 + 3] = 0.f;
        }
    }
}

// ================================================================ host
extern "C" void kernel_launch(void* const* d_in, const int* in_sizes, int n_in,
                              void* d_out, int out_size, void* d_ws, size_t ws_size,
                              hipStream_t stream) {
    const float* feat[5] = {
        (const float*)d_in[1], (const float*)d_in[2], (const float*)d_in[3],
        (const float*)d_in[4], (const float*)d_in[5]};
    const float* w_inter = (const float*)d_in[6];
    const float* b_inter = (const float*)d_in[7];
    const float* w_cls   = (const float*)d_in[8];
    const float* b_cls   = (const float*)d_in[9];
    const float* w_reg   = (const float*)d_in[10];
    const float* b_reg   = (const float*)d_in[11];

    float* out     = (float*)d_out;
    float* out_cls = out;                       // 159882*2
    float* out_reg = out + 319764;              // 159882*4
    float* out_roi = out + 959292;              // 1000*4
    float* out_anc = out + 963292;              // 159882*4

    static const int GH[5]    = {200, 100, 50, 25, 13};
    static const int GW[5]    = {200, 100, 50, 25, 13};
    static const int ABASE[5] = {0, 120000, 150000, 157500, 159375};

    // ---- workspace carve (~6.5 MB total)
    char* p = (char*)d_ws;
    size_t off = 0;
    auto alloc = [&](size_t bytes) -> void* {
        void* r = p + off;
        off = (off + bytes + 255) & ~(size_t)255;
        return r;
    };
    float* Wt      = (float*)alloc((size_t)2304 * 256 * 4);
    u64*   keys    = (u64*)  alloc((size_t)A_TOT * 8);
    u32*   hist    = (u32*)  alloc((size_t)HIST_BINS * 4);
    u32*   hist2   = (u32*)  alloc((size_t)HIST2_BINS * 4);
    u32*   counters= (u32*)  alloc(256);
    u64*   surv    = (u64*)  alloc((size_t)SURV_CAP * 8);
    float* boxes4k = (float*)alloc((size_t)PRE_NMS * 4 * 4);
    u64*   finmask = (u64*)  alloc(64 * 8);
    u64*   supmat  = (u64*)  alloc((size_t)PRE_NMS * NWORDS * 8);
    u64*   keepw   = (u64*)  alloc(64 * 8);
    (void)ws_size;

    // ---- host anchor base table, float32 to match np (round half-even)
    BaseTab bt;
    {
        const float sizes[5] = {32.f, 64.f, 128.f, 256.f, 512.f};
        const float asp[3] = {0.5f, 1.0f, 2.0f};
        for (int l = 0; l < 5; ++l)
            for (int a = 0; a < 3; ++a) {
                float hr = sqrtf(asp[a]);
                float wr = 1.0f / hr;
                float wsf = sizes[l] * wr;
                float hsf = sizes[l] * hr;
                bt.v[(l * 3 + a) * 4 + 0] = rintf(-wsf / 2.0f);
                bt.v[(l * 3 + a) * 4 + 1] = rintf(-hsf / 2.0f);
                bt.v[(l * 3 + a) * 4 + 2] = rintf( wsf / 2.0f);
                bt.v[(l * 3 + a) * 4 + 3] = rintf( hsf / 2.0f);
            }
    }

    hipMemsetAsync(hist, 0, (size_t)HIST_BINS * 4, stream);
    hipMemsetAsync(hist2, 0, (size_t)HIST2_BINS * 4, stream);
    hipMemsetAsync(counters, 0, 256, stream);

    wt_k<<<2304, 256, 0, stream>>>(w_inter, Wt);

    for (int l = 0; l < 5; ++l) {
        dim3 grid((GW[l] + XSTRIP - 1) / XSTRIP, GH[l]);
        conv_head_fused<<<grid, 192, 0, stream>>>(
            feat[l], Wt, b_inter, w_cls, b_cls, w_reg, b_reg,
            out_cls, out_reg, GH[l], GW[l], ABASE[l]);
    }
    int nbA = (A_TOT + 255) / 256;
    anchors_k<<<nbA, 256, 0, stream>>>(out_anc, bt);
    score_k<<<nbA, 256, 0, stream>>>(out_cls, out_reg, out_anc, keys, hist);
    topk_thresh<<<1, 1024, 0, stream>>>(hist, counters);
    hist2_k<<<nbA, 256, 0, stream>>>(keys, counters, hist2);
    thresh2_k<<<1, 1024, 0, stream>>>(hist2, counters);
    compact_k<<<nbA, 256, 0, stream>>>(keys, counters, surv);
    sort_topk<<<1, 1024, 0, stream>>>(surv, counters, out_reg, out_anc, boxes4k, finmask);
    supmat_k<<<dim3(NWORDS, NWORDS), 64, 0, stream>>>(boxes4k, supmat);
    nms_scan_k<<<1, 64, 0, stream>>>(supmat, finmask, keepw);
    output_k<<<1, 1024, 0, stream>>>(keepw, boxes4k, out_roi);
}

// Round 7
// 4101.530 us; speedup vs baseline: 1.1109x; 1.1109x over previous
//
#include <hip/hip_runtime.h>
#include <cmath>
#include <cstdint>

typedef unsigned int u32;
typedef unsigned long long u64;
typedef float v2f __attribute__((ext_vector_type(2)));

#define A_TOT   159882
#define PRE_NMS 4000
#define POST_NMS 1000
#define NWORDS  63            // ceil(4000/64)
#define HIST_BINS 131072
#define HIST2_BINS 32768
#define SURV_CAP 8192
#define MONO_NEG_INF 0x007FFFFFu

struct BaseTab { float v[60]; };   // [level][aspect][4]

__device__ inline u32 mono32f(float s) {
    u32 u = __float_as_uint(s);
    return (u & 0x80000000u) ? ~u : (u | 0x80000000u);
}

// XLA:CPU / cephes vectorized expf (verified passing in r6 — DO NOT TOUCH)
__device__ inline float pexp_f(float x0) {
    float x = fminf(x0, 88.3762626647950f);
    x = fmaxf(x, -88.3762626647949f);
    float m = floorf(__builtin_fmaf(x, 1.44269504088896341f, 0.5f));
    float r = __builtin_fmaf(m, -0.693359375f, x);
    r = __builtin_fmaf(m, 2.12194440e-4f, r);
    float z = r * r;
    float y = 1.9875691500E-4f;
    y = __builtin_fmaf(y, r, 1.3981999507E-3f);
    y = __builtin_fmaf(y, r, 8.3334519073E-3f);
    y = __builtin_fmaf(y, r, 4.1665795894E-2f);
    y = __builtin_fmaf(y, r, 1.6666665459E-1f);
    y = __builtin_fmaf(y, r, 5.0000001201E-1f);
    y = __builtin_fmaf(y, z, r);
    y = y + 1.0f;
    return ldexpf(y, (int)m);
}

// verified decode chain (r6) — no fma, op order preserved
__device__ inline float4 decode_box(const float* __restrict__ reg,
                                    const float* __restrict__ anc,
                                    u32 i, bool* valid) {
#pragma clang fp contract(off)
    float x1 = anc[4 * i], y1 = anc[4 * i + 1], x2 = anc[4 * i + 2], y2 = anc[4 * i + 3];
    float acx = (x2 + x1) / 2.0f, acy = (y2 + y1) / 2.0f;
    float aw = x2 - x1, ah = y2 - y1;
    float t0 = reg[4 * i], t1 = reg[4 * i + 1], t2 = reg[4 * i + 2], t3 = reg[4 * i + 3];
    float cx = (t0 * aw) + acx;
    float cy = (t1 * ah) + acy;
    float w  = pexp_f(t2) * aw;
    float hh = pexp_f(t3) * ah;
    float bx1 = fminf(fmaxf(cx - w / 2.0f, 0.f), 1.f);
    float by1 = fminf(fmaxf(cy - hh / 2.0f, 0.f), 1.f);
    float bx2 = fminf(fmaxf(cx + w / 2.0f, 0.f), 1.f);
    float by2 = fminf(fmaxf(cy + hh / 2.0f, 0.f), 1.f);
    float wsz = bx2 - bx1, hsz = by2 - by1;
    *valid = (hsz >= 0.01f) && (wsz >= 0.01f);
    return make_float4(bx1, by1, bx2, by2);
}

// ---------------------------------------------------------------- W transpose to (ky,kx,c)-major
__global__ __launch_bounds__(256) void wt_k(const float* __restrict__ w,
                                            float* __restrict__ Wt) {
    int i = blockIdx.x * 256 + threadIdx.x;
    if (i >= 2304 * 256) return;
    int co = i & 255, knew = i >> 8;
    int g = knew >> 8;          // ky*3+kx
    int c = knew & 255;
    Wt[knew * 256 + co] = w[co * 2304 + c * 9 + g];
}

// ---------------------------------------------------------------- conv3x3 panel kernel
// Bit-exact Eigen chain: per element, k=(ky,kx,c) ascending, mul/add separate,
// kc=288 panel partials combined left-assoc. Block computes npan consecutive
// panels internally (npan=8: full conv; npan=1: one panel partial, grid.z=panel).
// Thread: cg=t&31 -> 8 c_out stride-32 (conflict-free ds_read); xg=t>>5 -> 4 x.
__global__ __launch_bounds__(256) void conv_panel(
    const float* __restrict__ feat, const float* __restrict__ Wt,
    float* __restrict__ part, int gh, int gw, int S, int npan, int lgs)
{
#pragma clang fp contract(off)
    __shared__ float Ws[32][256];   // 32 KB
    __shared__ float Xs[32][32];    // 4 KB (row stride fixed 32)
    const int t = threadIdx.x;
    const int nthr = blockDim.x;
    const int strip = (nthr >> 5) * 4;       // 32 (256thr) or 16 (128thr)
    const int cg = t & 31, xg = t >> 5;
    const int y  = blockIdx.y;
    const int x0 = blockIdx.x * strip;
    const int pb = blockIdx.z * npan;

    v2f tacc[8][2];
#pragma unroll
    for (int a = 0; a < 8; ++a) { tacc[a][0] = (v2f)0.f; tacc[a][1] = (v2f)0.f; }

    for (int pi = pb; pi < pb + npan; ++pi) {
        v2f pacc[8][2];
#pragma unroll
        for (int a = 0; a < 8; ++a) { pacc[a][0] = (v2f)0.f; pacc[a][1] = (v2f)0.f; }
        for (int j = 0; j < 9; ++j) {
            int s = pi * 9 + j;            // global step in (g outer, cb inner) order
            int g = s >> 3, cb = (s & 7) << 5;
            int ky = g / 3, kx = g - ky * 3;
            int yy = y + ky - 1;
            __syncthreads();
            for (int f4 = t; f4 < 2048; f4 += nthr) {
                int row = f4 >> 6, c4 = (f4 & 63) << 2;
                *(float4*)&Ws[row][c4] =
                    *(const float4*)&Wt[((g * 256 + cb + row) * 256) + c4];
            }
            for (int idx = t; idx < (strip << 5); idx += nthr) {
                int row = idx >> lgs, col = idx & (strip - 1);
                int xcol = x0 + kx - 1 + col;
                float v = 0.f;
                if (yy >= 0 && yy < gh && xcol >= 0 && xcol < gw)
                    v = feat[((cb + row) * gh + yy) * gw + xcol];
                Xs[row][col] = v;
            }
            __syncthreads();
#pragma unroll 4
            for (int kk = 0; kk < 32; ++kk) {
                float wv[8];
#pragma unroll
                for (int a = 0; a < 8; ++a) wv[a] = Ws[kk][cg + 32 * a];
                v2f xlo = *(const v2f*)&Xs[kk][xg * 4];
                v2f xhi = *(const v2f*)&Xs[kk][xg * 4 + 2];
#pragma unroll
                for (int a = 0; a < 8; ++a) {
                    v2f w2; w2[0] = wv[a]; w2[1] = wv[a];
                    v2f p0 = w2 * xlo;                 // separate round
                    pacc[a][0] = pacc[a][0] + p0;      // separate round
                    v2f p1 = w2 * xhi;
                    pacc[a][1] = pacc[a][1] + p1;
                }
            }
        }
#pragma unroll
        for (int a = 0; a < 8; ++a) {
            tacc[a][0] = tacc[a][0] + pacc[a][0];      // left-assoc panel combine
            tacc[a][1] = tacc[a][1] + pacc[a][1];
        }
    }
    float* op = part + (size_t)blockIdx.z * 256 * S;
#pragma unroll
    for (int a = 0; a < 8; ++a) {
        int c = cg + 32 * a;
#pragma unroll
        for (int b = 0; b < 4; ++b) {
            int x = x0 + xg * 4 + b;
            if (x < gw) op[(size_t)c * S + y * gw + x] = tacc[a][b >> 1][b & 1];
        }
    }
}

// ---------------------------------------------------------------- finalize: sum panels (in order) + bias + relu, in place
__global__ __launch_bounds__(256) void finalize_k(float* __restrict__ part,
                                                  const float* __restrict__ bias,
                                                  int S, int npan) {
#pragma clang fp contract(off)
    int c = blockIdx.y;
    int s = blockIdx.x * 256 + threadIdx.x;
    if (s >= S) return;
    size_t i = (size_t)c * S + s;
    float v = part[i];
    for (int p = 1; p < npan; ++p)
        v = v + part[(size_t)p * 256 * S + i];         // strict panel order
    part[i] = fmaxf(v + bias[c], 0.f);
}

// ---------------------------------------------------------------- 1x1 heads (c-ascending mul/add chain, r6 numerics)
__global__ __launch_bounds__(256) void head1x1(
    const float* __restrict__ h, const float* __restrict__ wc,
    const float* __restrict__ bc, const float* __restrict__ wr,
    const float* __restrict__ br, float* __restrict__ cls_out,
    float* __restrict__ reg_out, int S, int abase)
{
#pragma clang fp contract(off)
    int s0 = blockIdx.x * 1024 + threadIdx.x;
    float ac[4][6]  = {{0.f}};
    float ar[4][12] = {{0.f}};
    for (int c = 0; c < 256; ++c) {
        const float* hc = h + (size_t)c * S;
        float v[4];
#pragma unroll
        for (int q = 0; q < 4; ++q) {
            int s = s0 + q * 256;
            v[q] = (s < S) ? hc[s] : 0.f;
        }
#pragma unroll
        for (int ch = 0; ch < 6; ++ch) {
            float wv = wc[ch * 256 + c];
#pragma unroll
            for (int q = 0; q < 4; ++q) {
                float prod = wv * v[q];
                ac[q][ch] = ac[q][ch] + prod;
            }
        }
#pragma unroll
        for (int ch = 0; ch < 12; ++ch) {
            float wv = wr[ch * 256 + c];
#pragma unroll
            for (int q = 0; q < 4; ++q) {
                float prod = wv * v[q];
                ar[q][ch] = ar[q][ch] + prod;
            }
        }
    }
#pragma unroll
    for (int q = 0; q < 4; ++q) {
        int s = s0 + q * 256;
        if (s >= S) continue;
        long b2 = (long)abase + (long)s * 3;
#pragma unroll
        for (int a = 0; a < 3; ++a) {
#pragma unroll
            for (int c2 = 0; c2 < 2; ++c2)
                cls_out[(b2 + a) * 2 + c2] = ac[q][a * 2 + c2] + bc[a * 2 + c2];
#pragma unroll
            for (int d = 0; d < 4; ++d)
                reg_out[(b2 + a) * 4 + d] = ar[q][a * 4 + d] + br[a * 4 + d];
        }
    }
}

// ---------------------------------------------------------------- anchors
__global__ __launch_bounds__(256) void anchors_k(float* __restrict__ anc, BaseTab bt) {
#pragma clang fp contract(off)
    int i = blockIdx.x * 256 + threadIdx.x;
    if (i >= A_TOT) return;
    int l, base, gw, str;
    if (i < 120000)      { l = 0; base = 0;      gw = 200; str = 4;  }
    else if (i < 150000) { l = 1; base = 120000; gw = 100; str = 8;  }
    else if (i < 157500) { l = 2; base = 150000; gw = 50;  str = 16; }
    else if (i < 159375) { l = 3; base = 157500; gw = 25;  str = 32; }
    else                 { l = 4; base = 159375; gw = 13;  str = 61; }
    int j = i - base;
    int s = j / 3;
    int a = j - s * 3;
    int y = s / gw;
    int x = s - y * gw;
    float sx = (float)(x * str), sy = (float)(y * str);
    const float* bb = &bt.v[(l * 3 + a) * 4];
    anc[4 * i + 0] = (sx + bb[0]) / 800.0f;
    anc[4 * i + 1] = (sy + bb[1]) / 800.0f;
    anc[4 * i + 2] = (sx + bb[2]) / 800.0f;
    anc[4 * i + 3] = (sy + bb[3]) / 800.0f;
}

// ---------------------------------------------------------------- f32 score + key + hist
__global__ __launch_bounds__(256) void score_k(
    const float* __restrict__ cls, const float* __restrict__ reg,
    const float* __restrict__ anc,
    u64* __restrict__ keys, u32* __restrict__ hist)
{
#pragma clang fp contract(off)
    int i = blockIdx.x * 256 + threadIdx.x;
    if (i >= A_TOT) return;
    float l0 = cls[2 * i], l1 = cls[2 * i + 1];
    float m  = fmaxf(l0, l1);
    float e0 = pexp_f(l0 - m);
    float e1 = pexp_f(l1 - m);
    float sum = e0 + e1;
    float sc  = e1 / sum;

    bool valid;
    (void)decode_box(reg, anc, (u32)i, &valid);
    float score = valid ? sc : -INFINITY;
    u32 u = mono32f(score);
    keys[i] = ((u64)u << 32) | (u32)(~(u32)i);   // desc score, asc index
    atomicAdd(&hist[u >> 15], 1u);
}

// ---------------------------------------------------------------- coarse threshold bin
__global__ __launch_bounds__(1024) void topk_thresh(const u32* __restrict__ hist,
                                                    u32* __restrict__ counters) {
    __shared__ u32 part[1024];
    int t = threadIdx.x;
    u32 s = 0;
    for (int q = 0; q < 128; ++q) s += hist[HIST_BINS - 1 - (t * 128 + q)];
    part[t] = s;
    __syncthreads();
    if (t == 0) {
        u32 cum = 0, cumBefore = 0;
        int tc = 1023;
        for (int c = 0; c < 1024; ++c) {
            if (cum + part[c] >= PRE_NMS) { tc = c; cumBefore = cum; break; }
            cum += part[c];
        }
        u32 cum2 = cumBefore;
        int bstar = 0;
        for (int q = 0; q < 128; ++q) {
            int b = HIST_BINS - 1 - (tc * 128 + q);
            u32 hv = hist[b];
            if (cum2 + hv >= PRE_NMS) { bstar = b; break; }
            cum2 += hv;
        }
        counters[0] = (u32)bstar;
        counters[1] = cum2;
    }
}

// ---------------------------------------------------------------- fine histogram in bstar bin
__global__ __launch_bounds__(256) void hist2_k(const u64* __restrict__ keys,
                                               const u32* __restrict__ counters,
                                               u32* __restrict__ hist2) {
    int i = blockIdx.x * 256 + threadIdx.x;
    if (i >= A_TOT) return;
    u32 u = (u32)(keys[i] >> 32);
    if ((u >> 15) == counters[0]) atomicAdd(&hist2[u & 0x7FFF], 1u);
}

// ---------------------------------------------------------------- exact 32-bit cutoff
__global__ __launch_bounds__(1024) void thresh2_k(const u32* __restrict__ hist2,
                                                  u32* __restrict__ counters) {
    __shared__ u32 part[1024];
    int t = threadIdx.x;
    u32 s = 0;
    for (int q = 0; q < 32; ++q) s += hist2[HIST2_BINS - 1 - (t * 32 + q)];
    part[t] = s;
    __syncthreads();
    if (t == 0) {
        u32 bstar = counters[0];
        u32 cum = counters[1];
        int tc = 1023;
        u32 cumBefore = cum;
        for (int c = 0; c < 1024; ++c) {
            if (cum + part[c] >= PRE_NMS) { tc = c; cumBefore = cum; break; }
            cum += part[c];
        }
        u32 cum2 = cumBefore;
        u32 low = 0;
        for (int q = 0; q < 32; ++q) {
            int b = HIST2_BINS - 1 - (tc * 32 + q);
            u32 hv = hist2[b];
            if (cum2 + hv >= PRE_NMS) { low = (u32)b; break; }
            cum2 += hv;
        }
        counters[3] = (bstar << 15) | low;   // exact monotone-u cutoff
    }
}

// ---------------------------------------------------------------- compact survivors (exact)
__global__ __launch_bounds__(256) void compact_k(const u64* __restrict__ keys,
                                                 u32* __restrict__ counters,
                                                 u64* __restrict__ surv) {
    int i = blockIdx.x * 256 + threadIdx.x;
    if (i >= A_TOT) return;
    u32 cut = counters[3];
    u64 k = keys[i];
    if ((u32)(k >> 32) >= cut) {
        u32 slot = atomicAdd(&counters[2], 1u);
        if (slot < SURV_CAP) surv[slot] = k;
    }
}

// ---------------------------------------------------------------- bitonic sort + gather (recompute decode)
__global__ __launch_bounds__(1024) void sort_topk(
    const u64* __restrict__ surv, const u32* __restrict__ counters,
    const float* __restrict__ reg, const float* __restrict__ anc,
    float* __restrict__ boxes4k, u64* __restrict__ finmask)
{
    __shared__ u64 K[SURV_CAP];   // 64 KB
    int t = threadIdx.x;
    u32 n = counters[2];
    if (n > SURV_CAP) n = SURV_CAP;
    for (int p = t; p < SURV_CAP; p += 1024) K[p] = (p < (int)n) ? surv[p] : 0ull;
    __syncthreads();
    for (int k = 2; k <= SURV_CAP; k <<= 1) {
        for (int j = k >> 1; j > 0; j >>= 1) {
            for (int p = t; p < SURV_CAP / 2; p += 1024) {
                int i = 2 * p - (p & (j - 1));
                int pr = i + j;
                bool desc = ((i & k) == 0);
                u64 a = K[i], b = K[pr];
                if (desc ? (a < b) : (a > b)) { K[i] = b; K[pr] = a; }
            }
            __syncthreads();
        }
    }
    for (int jj = t; jj < PRE_NMS; jj += 1024) {
        u64 key = K[jj];
        u32 u = (u32)(key >> 32);
        float b0 = 0.f, b1 = 0.f, b2 = 0.f, b3 = 0.f;
        if (u > MONO_NEG_INF) {
            u32 idx = ~(u32)key;
            bool valid;
            float4 bx = decode_box(reg, anc, idx, &valid);
            b0 = bx.x; b1 = bx.y; b2 = bx.z; b3 = bx.w;
        }
        boxes4k[4 * jj + 0] = b0;
        boxes4k[4 * jj + 1] = b1;
        boxes4k[4 * jj + 2] = b2;
        boxes4k[4 * jj + 3] = b3;
    }
    if (t < NWORDS) {
        u64 wmask = 0;
        for (int b = 0; b < 64; ++b) {
            int jj = t * 64 + b;
            if (jj < PRE_NMS) {
                u32 u = (u32)(K[jj] >> 32);
                if (u > MONO_NEG_INF) wmask |= (1ull << b);
            }
        }
        finmask[t] = wmask;
    }
}

// ---------------------------------------------------------------- suppression matrix (f32, np op order)
__global__ __launch_bounds__(64) void supmat_k(const float* __restrict__ boxes4k,
                                               u64* __restrict__ sup) {
#pragma clang fp contract(off)
    __shared__ float cb[64][4];
    int rb = blockIdx.y, cbk = blockIdx.x;
    int tl = threadIdx.x;
    int j = cbk * 64 + tl;
    if (j < PRE_NMS) {
        cb[tl][0] = boxes4k[4 * j + 0];
        cb[tl][1] = boxes4k[4 * j + 1];
        cb[tl][2] = boxes4k[4 * j + 2];
        cb[tl][3] = boxes4k[4 * j + 3];
    } else {
        cb[tl][0] = cb[tl][1] = cb[tl][2] = cb[tl][3] = 0.f;
    }
    __syncthreads();
    int i = rb * 64 + tl;
    if (i >= PRE_NMS) return;
    float ax1 = boxes4k[4 * i + 0], ay1 = boxes4k[4 * i + 1];
    float ax2 = boxes4k[4 * i + 2], ay2 = boxes4k[4 * i + 3];
    float aarea = fmaxf(ax2 - ax1, 0.f) * fmaxf(ay2 - ay1, 0.f);
    u64 w = 0;
    for (int q = 0; q < 64; ++q) {
        int jg = cbk * 64 + q;
        if (jg >= PRE_NMS || jg <= i) continue;
        float bx1 = cb[q][0], by1 = cb[q][1], bx2 = cb[q][2], by2 = cb[q][3];
        float barea = fmaxf(bx2 - bx1, 0.f) * fmaxf(by2 - by1, 0.f);
        float lx = fmaxf(ax1, bx1), ly = fmaxf(ay1, by1);
        float rx = fminf(ax2, bx2), ry = fminf(ay2, by2);
        float iw = fmaxf(rx - lx, 0.f), ih = fmaxf(ry - ly, 0.f);
        float inter = iw * ih;
        float uni = (aarea + barea) - inter;
        float iou = (uni > 0.f) ? inter / uni : 0.f;
        if (iou > 0.7f) w |= (1ull << q);
    }
    sup[(size_t)i * NWORDS + cbk] = w;
}

// ---------------------------------------------------------------- sequential NMS scan
__device__ inline u64 shfl_u64(u64 v, int lane) {
    int lo = __shfl((int)(u32)(v & 0xFFFFFFFFull), lane, 64);
    int hi = __shfl((int)(u32)(v >> 32), lane, 64);
    return ((u64)(u32)hi << 32) | (u32)lo;
}

__global__ __launch_bounds__(64) void nms_scan_k(const u64* __restrict__ sup,
                                                 const u64* __restrict__ finmask,
                                                 u64* __restrict__ keepw) {
    int lane = threadIdx.x;
    u64 keep = (lane < NWORDS) ? finmask[lane] : 0ull;
    u64 cur[8], nxt[8];
#pragma unroll
    for (int q = 0; q < 8; ++q)
        cur[q] = (lane < NWORDS) ? sup[(size_t)q * NWORDS + lane] : 0ull;
    for (int base = 0; base < PRE_NMS; base += 8) {
        int nb = base + 8;
#pragma unroll
        for (int q = 0; q < 8; ++q) {
            int i = nb + q;
            nxt[q] = (lane < NWORDS && i < PRE_NMS) ? sup[(size_t)i * NWORDS + lane] : 0ull;
        }
#pragma unroll
        for (int q = 0; q < 8; ++q) {
            int i = base + q;
            int wi = i >> 6, bi = i & 63;
            u64 kw = shfl_u64(keep, wi);
            if ((kw >> bi) & 1ull) keep &= ~cur[q];
        }
#pragma unroll
        for (int q = 0; q < 8; ++q) cur[q] = nxt[q];
    }
    if (lane < NWORDS) keepw[lane] = keep;
}

// ---------------------------------------------------------------- final compaction
__global__ __launch_bounds__(1024) void output_k(const u64* __restrict__ keepw,
                                                 const float* __restrict__ boxes4k,
                                                 float* __restrict__ roi_out) {
    __shared__ u32 pref[NWORDS + 1];
    int t = threadIdx.x;
    if (t == 0) {
        u32 run = 0;
        for (int w = 0; w < NWORDS; ++w) { pref[w] = run; run += (u32)__popcll(keepw[w]); }
        pref[NWORDS] = run;
    }
    __syncthreads();
    u32 total = pref[NWORDS];
    u32 nk = total < (u32)POST_NMS ? total : (u32)POST_NMS;
    for (int j = t; j < PRE_NMS; j += 1024) {
        int wi = j >> 6, bi = j & 63;
        u64 kw = keepw[wi];
        if ((kw >> bi) & 1ull) {
            u32 rank = pref[wi] + (u32)__popcll(kw & ((1ull << bi) - 1ull));
            if (rank < (u32)POST_NMS) {
                roi_out[4 * rank + 0] = boxes4k[4 * j + 0];
                roi_out[4 * rank + 1] = boxes4k[4 * j + 1];
                roi_out[4 * rank + 2] = boxes4k[4 * j + 2];
                roi_out[4 * rank + 3] = boxes4k[4 * j + 3];
            }
        }
    }
    for (int r2 = t; r2 < POST_NMS; r2 += 1024) {
        if ((u32)r2 >= nk) {
            roi_out[4 * r2 + 0] = 0.f;
            roi_out[4 * r2 + 1] = 0.f;
            roi_out[4 * r2 + 2] = 0.f;
            roi_out[4 * r2 + 3] = 0.f;
        }
    }
}

// ================================================================ host
extern "C" void kernel_launch(void* const* d_in, const int* in_sizes, int n_in,
                              void* d_out, int out_size, void* d_ws, size_t ws_size,
                              hipStream_t stream) {
    const float* feat[5] = {
        (const float*)d_in[1], (const float*)d_in[2], (const float*)d_in[3],
        (const float*)d_in[4], (const float*)d_in[5]};
    const float* w_inter = (const float*)d_in[6];
    const float* b_inter = (const float*)d_in[7];
    const float* w_cls   = (const float*)d_in[8];
    const float* b_cls   = (const float*)d_in[9];
    const float* w_reg   = (const float*)d_in[10];
    const float* b_reg   = (const float*)d_in[11];

    float* out     = (float*)d_out;
    float* out_cls = out;                       // 159882*2
    float* out_reg = out + 319764;              // 159882*4
    float* out_roi = out + 959292;              // 1000*4
    float* out_anc = out + 963292;              // 159882*4

    static const int GH[5]    = {200, 100, 50, 25, 13};
    static const int GW[5]    = {200, 100, 50, 25, 13};
    static const int SL[5]    = {40000, 10000, 2500, 625, 169};
    static const int ABASE[5] = {0, 120000, 150000, 157500, 159375};
    static const int NPAN_ST[5] = {1, 1, 8, 8, 8};   // panel-partial slots stored
    static const int BLKT[5]  = {256, 256, 256, 256, 128};

    // ---- workspace carve (~85 MB total)
    char* p = (char*)d_ws;
    size_t off = 0;
    auto alloc = [&](size_t bytes) -> void* {
        void* r = p + off;
        off = (off + bytes + 255) & ~(size_t)255;
        return r;
    };
    float* Wt      = (float*)alloc((size_t)2304 * 256 * 4);
    float* part[5];
    for (int l = 0; l < 5; ++l)
        part[l] = (float*)alloc((size_t)NPAN_ST[l] * 256 * SL[l] * 4);
    u64*   keys    = (u64*)  alloc((size_t)A_TOT * 8);
    u32*   hist    = (u32*)  alloc((size_t)HIST_BINS * 4);
    u32*   hist2   = (u32*)  alloc((size_t)HIST2_BINS * 4);
    u32*   counters= (u32*)  alloc(256);
    u64*   surv    = (u64*)  alloc((size_t)SURV_CAP * 8);
    float* boxes4k = (float*)alloc((size_t)PRE_NMS * 4 * 4);
    u64*   finmask = (u64*)  alloc(64 * 8);
    u64*   supmat  = (u64*)  alloc((size_t)PRE_NMS * NWORDS * 8);
    u64*   keepw   = (u64*)  alloc(64 * 8);
    (void)ws_size;

    // ---- host anchor base table, float32 to match np (round half-even)
    BaseTab bt;
    {
        const float sizes[5] = {32.f, 64.f, 128.f, 256.f, 512.f};
        const float asp[3] = {0.5f, 1.0f, 2.0f};
        for (int l = 0; l < 5; ++l)
            for (int a = 0; a < 3; ++a) {
                float hr = sqrtf(asp[a]);
                float wr = 1.0f / hr;
                float wsf = sizes[l] * wr;
                float hsf = sizes[l] * hr;
                bt.v[(l * 3 + a) * 4 + 0] = rintf(-wsf / 2.0f);
                bt.v[(l * 3 + a) * 4 + 1] = rintf(-hsf / 2.0f);
                bt.v[(l * 3 + a) * 4 + 2] = rintf( wsf / 2.0f);
                bt.v[(l * 3 + a) * 4 + 3] = rintf( hsf / 2.0f);
            }
    }

    hipMemsetAsync(hist, 0, (size_t)HIST_BINS * 4, stream);
    hipMemsetAsync(hist2, 0, (size_t)HIST2_BINS * 4, stream);
    hipMemsetAsync(counters, 0, 256, stream);

    wt_k<<<2304, 256, 0, stream>>>(w_inter, Wt);

    // conv: levels 0/1 -> full 8-panel chain per block; levels 2-4 -> 8-way panel split
    for (int l = 0; l < 5; ++l) {
        int nthr = BLKT[l];
        int strip = (nthr >> 5) * 4;
        int lgs = (strip == 32) ? 5 : 4;
        int xtiles = (GW[l] + strip - 1) / strip;
        int zsplit = NPAN_ST[l];                 // 1 or 8
        int npan_in = (zsplit == 1) ? 8 : 1;
        dim3 grid(xtiles, GH[l], zsplit);
        conv_panel<<<grid, nthr, 0, stream>>>(feat[l], Wt, part[l],
                                              GH[l], GW[l], SL[l], npan_in, lgs);
    }
    // finalize: sum panel partials in order + bias + relu (in place -> h)
    for (int l = 0; l < 5; ++l) {
        dim3 grid((SL[l] + 255) / 256, 256);
        finalize_k<<<grid, 256, 0, stream>>>(part[l], b_inter, SL[l], NPAN_ST[l]);
    }
    // heads
    for (int l = 0; l < 5; ++l) {
        int nb = (SL[l] + 1023) / 1024;
        head1x1<<<nb, 256, 0, stream>>>(part[l], w_cls, b_cls, w_reg, b_reg,
                                        out_cls, out_reg, SL[l], ABASE[l]);
    }
    int nbA = (A_TOT + 255) / 256;
    anchors_k<<<nbA, 256, 0, stream>>>(out_anc, bt);
    score_k<<<nbA, 256, 0, stream>>>(out_cls, out_reg, out_anc, keys, hist);
    topk_thresh<<<1, 1024, 0, stream>>>(hist, counters);
    hist2_k<<<nbA, 256, 0, stream>>>(keys, counters, hist2);
    thresh2_k<<<1, 1024, 0, stream>>>(hist2, counters);
    compact_k<<<nbA, 256, 0, stream>>>(keys, counters, surv);
    sort_topk<<<1, 1024, 0, stream>>>(surv, counters, out_reg, out_anc, boxes4k, finmask);
    supmat_k<<<dim3(NWORDS, NWORDS), 64, 0, stream>>>(boxes4k, supmat);
    nms_scan_k<<<1, 64, 0, stream>>>(supmat, finmask, keepw);
    output_k<<<1, 1024, 0, stream>>>(keepw, boxes4k, out_roi);
}